// Round 2
// baseline (426.390 us; speedup 1.0000x reference)
//
#include <hip/hip_runtime.h>

typedef unsigned short ushort_t;
typedef unsigned int   uint_t;
typedef __attribute__((ext_vector_type(8))) short  short8;
typedef __attribute__((ext_vector_type(4))) float  float4v;
typedef __attribute__((ext_vector_type(4))) uint_t uint4v;

#define B_    16
#define CIN_  320
#define COUT_ 320
#define NLORA 50
#define R_    4

// workspace layout (bytes)
#define XPAD_ELEMS ((size_t)B_ * 66 * 66 * CIN_)   // bf16 NHWC padded x
#define WEFF_OFF   (XPAD_ELEMS * 2)

__device__ __forceinline__ ushort_t bf16rne(float f) {
  uint_t u = __float_as_uint(f);
  u = (u + 0x7FFFu + ((u >> 16) & 1u)) >> 16;
  return (ushort_t)u;
}

#define GLDS16(gp, lp)                                                          \
  __builtin_amdgcn_global_load_lds(                                             \
      (const __attribute__((address_space(1))) void*)(gp),                      \
      (__attribute__((address_space(3))) void*)(lp), 16, 0, 0)

// ---------------------------------------------------------------------------
// Kernel 0: zero the 1-px halo of x_pad (borders only; 2.66 MB, not 44.6).
// 650 blocks x 256 thr, one uint4 (8 ch) per thread. 10400 uint4 per image.
// ---------------------------------------------------------------------------
__global__ __launch_bounds__(256)
void zero_borders(ushort_t* __restrict__ x_pad) {
  int g = blockIdx.x * 256 + threadIdx.x;        // 0 .. 166399
  int b = g / 10400;
  int r = g - b * 10400;
  int cell = r / 40;
  int v = r - cell * 40;
  int hh, ww;
  if (cell < 66)       { hh = 0;          ww = cell; }
  else if (cell < 132) { hh = 65;         ww = cell - 66; }
  else if (cell < 196) { hh = cell - 131; ww = 0; }
  else                 { hh = cell - 195; ww = 65; }
  *(uint4v*)(x_pad + (((size_t)(b * 66 + hh)) * 66 + ww) * CIN_ + v * 8) = (uint4v)0u;
}

// ---------------------------------------------------------------------------
// Kernel 1: x [B][C][H][W] fp32 -> x_pad [B][66][66][C] bf16 (interior).
// Vectorized: float4 global loads, LDS transpose t[64][65] (conflict-free),
// uint4 (8ch bf16) stores.
// ---------------------------------------------------------------------------
__global__ __launch_bounds__(256)
void pad_convert(const float* __restrict__ x, ushort_t* __restrict__ x_pad) {
  __shared__ float t[64][65];
  const int cc  = blockIdx.x;   // channel chunk 0..4 (64 ch each)
  const int h   = blockIdx.y;   // 0..63
  const int b   = blockIdx.z;
  const int tid = threadIdx.x;
  #pragma unroll
  for (int it = 0; it < 4; ++it) {
    int g  = it * 256 + tid;
    int cl = g >> 4, w4 = (g & 15) * 4;
    float4v v = *(const float4v*)(x +
        (((size_t)(b * CIN_ + cc * 64 + cl)) * 64 + h) * 64 + w4);
    t[cl][w4 + 0] = v.x; t[cl][w4 + 1] = v.y;
    t[cl][w4 + 2] = v.z; t[cl][w4 + 3] = v.w;
  }
  __syncthreads();
  #pragma unroll
  for (int it = 0; it < 2; ++it) {
    int g   = it * 256 + tid;
    int ch8 = g & 7;          // 8-channel group
    int w   = g >> 3;         // 0..63
    uint4v p;
    p.x = (uint_t)bf16rne(t[ch8 * 8 + 0][w]) | ((uint_t)bf16rne(t[ch8 * 8 + 1][w]) << 16);
    p.y = (uint_t)bf16rne(t[ch8 * 8 + 2][w]) | ((uint_t)bf16rne(t[ch8 * 8 + 3][w]) << 16);
    p.z = (uint_t)bf16rne(t[ch8 * 8 + 4][w]) | ((uint_t)bf16rne(t[ch8 * 8 + 5][w]) << 16);
    p.w = (uint_t)bf16rne(t[ch8 * 8 + 6][w]) | ((uint_t)bf16rne(t[ch8 * 8 + 7][w]) << 16);
    *(uint4v*)(x_pad + (((size_t)(b * 66 + h + 1)) * 66 + (w + 1)) * CIN_ + cc * 64 + ch8 * 8) = p;
  }
}

// ---------------------------------------------------------------------------
// Kernel 2: merged per-sample weights, LDS-staged (coalesced float4 loads).
//   W_eff[b][tap][o][c] = bf16(conv_w[o][c][tap] + act*sum_r up[l][o][r]*down[l][r][c][tap])
// ---------------------------------------------------------------------------
__global__ __launch_bounds__(320)
void merge_weights(const float* __restrict__ conv_w, const float* __restrict__ down_w,
                   const float* __restrict__ up_w,  const void* __restrict__ lora,
                   ushort_t* __restrict__ W_eff) {
  __shared__ __align__(16) float cw[2880];        // conv_w[o][*][*]
  __shared__ __align__(16) float dw[4 * 2880];    // down_w[l][*][*][*]
  const int o = blockIdx.x;       // 0..319
  const int b = blockIdx.y;       // 0..15
  const int c = threadIdx.x;      // 0..319

  // int32 vs int64 lora_id detection (first 64 B valid either way)
  const int* p32 = (const int*)lora;
  bool odd0 = true;
  #pragma unroll
  for (int i = 1; i < 16; i += 2) odd0 = odd0 && (p32[i] == 0);
  long long raw = odd0 ? ((const long long*)lora)[b] : (long long)p32[b];
  long long idx = (raw >= 0) ? (raw >> 2) : -(((-raw) + 3) >> 2);
  float act = (idx >= 0) ? 1.0f : 0.0f;
  int l = (int)(idx < 0 ? 0 : (idx > (NLORA - 1) ? (NLORA - 1) : idx));

  const float4v* cs = (const float4v*)(conv_w + (size_t)o * 2880);
  for (int g = c; g < 720; g += 320) ((float4v*)cw)[g] = cs[g];
  const float4v* ds = (const float4v*)(down_w + (size_t)l * 11520);
  for (int g = c; g < 2880; g += 320) ((float4v*)dw)[g] = ds[g];
  __syncthreads();

  float up[R_];
  #pragma unroll
  for (int r = 0; r < R_; ++r)
    up[r] = up_w[((size_t)l * COUT_ + o) * R_ + r] * act;

  #pragma unroll
  for (int tap = 0; tap < 9; ++tap) {
    float v = cw[c * 9 + tap];
    #pragma unroll
    for (int r = 0; r < R_; ++r)
      v += up[r] * dw[r * 2880 + c * 9 + tap];
    W_eff[(((size_t)b * 9 + tap) * COUT_ + o) * CIN_ + c] = bf16rne(v);
  }
}

// ---------------------------------------------------------------------------
// Kernel 3: implicit-GEMM conv, bf16 MFMA 16x16x32 fp32-acc.
// 512 thr (8 waves). Block tile: M=512 (8 rows x 64 cols), N=64 out-ch,
// K chunks of 32 ch x 9 taps. Wave wv owns output row h0+wv (4m x 4n subs).
// Staging via global_load_lds (16B, lane-linear LDS); swizzle on the GLOBAL
// address: slot s at (row,ww) holds ch (s ^ ((ww>>1)&3))*8 -> any 8
// consecutive lanes of an MFMA ds_read hit 8 distinct 4-bank groups.
// LDS 79 KB -> 2 blocks/CU (16 waves/CU).
// ---------------------------------------------------------------------------
__global__ __launch_bounds__(512, 4)
void conv_main(const ushort_t* __restrict__ x_pad, const ushort_t* __restrict__ W_eff,
               const float* __restrict__ conv_b, float* __restrict__ out) {
  __shared__ __align__(16) ushort_t xs[2640 * 8];   // [10][66][4 slots][8ch] = 42240 B
  __shared__ __align__(16) ushort_t wt[2304 * 8];   // [9][64][4 slots][8ch] = 36864 B

  const int tid = threadIdx.x;
  const int b   = blockIdx.z;
  const int h0  = blockIdx.x * 8;   // first output row
  const int o0  = blockIdx.y * 64;  // first output channel

  const int wv = tid >> 6;          // wave 0..7 -> output row h0+wv
  const int la = tid & 15;
  const int q  = (tid >> 4) & 3;

  // precompute staging global offsets (elements, sans c0)
  int xoff[6];
  #pragma unroll
  for (int it = 0; it < 6; ++it) {
    int g  = tid + it * 512;
    int hh = g / 264;
    int r  = g - hh * 264;
    int ww = r >> 2;
    int s  = r & 3;
    xoff[it] = ((b * 66 + h0 + hh) * 66 + ww) * CIN_ + (((s ^ (ww >> 1)) & 3) * 8);
  }
  int woff[5];
  #pragma unroll
  for (int it = 0; it < 5; ++it) {
    int g   = tid + it * 512;
    int tap = g >> 8;
    int o   = (g >> 2) & 63;
    int s   = g & 3;
    woff[it] = ((b * 9 + tap) * COUT_ + o0 + o) * CIN_ + (((s ^ (o >> 1)) & 3) * 8);
  }

  float4v acc[4][4];
  #pragma unroll
  for (int i = 0; i < 4; ++i)
    #pragma unroll
    for (int n = 0; n < 4; ++n) acc[i][n] = (float4v)0.0f;

  for (int c0 = 0; c0 < CIN_; c0 += 32) {
    __syncthreads();   // previous chunk fully consumed
    #pragma unroll
    for (int it = 0; it < 6; ++it) {
      int g = tid + it * 512;
      if (it < 5 || g < 2640) GLDS16(x_pad + xoff[it] + c0, xs + g * 8);
    }
    #pragma unroll
    for (int it = 0; it < 5; ++it) {
      int g = tid + it * 512;
      if (it < 4 || g < 2304) GLDS16(W_eff + woff[it] + c0, wt + g * 8);
    }
    __syncthreads();   // vmcnt(0) drain -> staged data visible

    #pragma unroll
    for (int tap = 0; tap < 9; ++tap) {
      const int kh = tap / 3, kw = tap % 3;
      short8 bf[4];
      #pragma unroll
      for (int n = 0; n < 4; ++n) {
        int o = n * 16 + la;
        bf[n] = *(const short8*)(wt + ((tap * 64 + o) * 4 + ((q ^ (o >> 1)) & 3)) * 8);
      }
      const int hh = wv + kh;
      #pragma unroll
      for (int i = 0; i < 4; ++i) {
        int ww = i * 16 + la + kw;
        short8 af = *(const short8*)(xs + ((hh * 66 + ww) * 4 + ((q ^ (ww >> 1)) & 3)) * 8);
        #pragma unroll
        for (int n = 0; n < 4; ++n)
          acc[i][n] = __builtin_amdgcn_mfma_f32_16x16x32_bf16(af, bf[n], acc[i][n], 0, 0, 0);
      }
    }
  }

  // Epilogue: direct float4 stores (reg r of acc[i][n] = spatial col
  // i*16 + q*4 + r, out-ch o0 + n*16 + la). L2 merges 64B halves into
  // full lines (both halves written by this wave).
  #pragma unroll
  for (int n = 0; n < 4; ++n) {
    const int o = o0 + n * 16 + la;
    const float bias = conv_b[o];
    #pragma unroll
    for (int i = 0; i < 4; ++i) {
      float4v v = acc[i][n];
      v += bias;
      *(float4v*)(out + (((size_t)b * COUT_ + o) * 64 + (h0 + wv)) * 64 + i * 16 + q * 4) = v;
    }
  }
}

// ---------------------------------------------------------------------------
extern "C" void kernel_launch(void* const* d_in, const int* in_sizes, int n_in,
                              void* d_out, int out_size, void* d_ws, size_t ws_size,
                              hipStream_t stream) {
  const float* x      = (const float*)d_in[0];
  const float* conv_w = (const float*)d_in[1];
  const float* conv_b = (const float*)d_in[2];
  const float* down_w = (const float*)d_in[3];
  const float* up_w   = (const float*)d_in[4];
  const void*  lora   = d_in[5];
  float* out = (float*)d_out;

  ushort_t* x_pad = (ushort_t*)d_ws;
  ushort_t* W_eff = (ushort_t*)((char*)d_ws + WEFF_OFF);

  zero_borders <<<dim3(650),        256, 0, stream>>>(x_pad);
  pad_convert  <<<dim3(5, 64, 16),  256, 0, stream>>>(x, x_pad);
  merge_weights<<<dim3(320, 16),    320, 0, stream>>>(conv_w, down_w, up_w, lora, W_eff);
  conv_main    <<<dim3(8, 5, 16),   512, 0, stream>>>(x_pad, W_eff, conv_b, out);
}